// Round 11
// baseline (94.769 us; speedup 1.0000x reference)
//
#include <hip/hip_runtime.h>

// ChamferLoss: B=4, N=M=8192, D=3, fp32. Scalar out.
// MFMA split-f16 (validated EXACT r6-r10), roles SWAPPED vs r10:
//   operand0 (A, rows) = REFERENCE points staged in LDS (a-form frags),
//   operand1 (B, cols) = QUERY points resident in registers (b-form frags).
// A lane's 16 C-regs = 16 ref rows for ONE query col -> the nearest-neighbor
// min is an IN-LANE register tree (VALU min3), not a cross-lane butterfly.
// r10's epilogue burned ~12.8us of DS-pipe on 160 shfl/wave; now it's
// 1 shfl_xor(32) per accumulator (4/wave). Coverage argument: 64 lanes x 16
// regs = 32x32 tile, col=lane&31 -> regs+hv-partner cover all 32 rows exactly
// once, so tree+xor32 needs no row-mapping knowledge.

#define BATCH   4
#define NPTS    8192
#define TPB     256
#define CSLICE  1024                 // ref points per block (LDS slice)
#define QT      4                    // query tiles (32 cols) per wave
#define QBLK    (4 * QT * 32)        // 512 queries per block
#define MT      (CSLICE / 32)        // 32 ref tiles per slice
#define SLICES  (NPTS / CSLICE)      // 8
#define QBLKS   (NPTS / QBLK)        // 16

typedef _Float16 h8   __attribute__((ext_vector_type(8)));
typedef float    f16v __attribute__((ext_vector_type(16)));

__device__ __forceinline__ void split16(float v, _Float16& hi, _Float16& lo) {
    hi = (_Float16)v;
    lo = (_Float16)(v - (float)hi);
}

__global__ __launch_bounds__(TPB) void chamfer_mfma(const float* __restrict__ xg,
                                                    const float* __restrict__ yg,
                                                    float* __restrict__ partial) {
    __shared__ h8 afrag[CSLICE * 2];          // 32 KB, de-interleaved (conflict-free)

    const int tid    = threadIdx.x;
    const int qblock = blockIdx.x;            // [0,16)
    const int slice  = blockIdx.y & (SLICES - 1);
    const int b      = blockIdx.y >> 3;       // SLICES == 8
    const int dir    = blockIdx.z;
    const int lane   = tid & 63, wave = tid >> 6;
    const int col    = lane & 31, hv = lane >> 5;

    const float* q = dir ? yg : xg;           // query side (cols, register B-frags)
    const float* r = dir ? xg : yg;           // reference side (rows, LDS A-frags)

    // ---- stage ref A-frags: 4 points per thread, de-interleaved layout ----
    const float* rbase = r + ((size_t)b * NPTS + slice * CSLICE) * 3;
#pragma unroll
    for (int i = 0; i < CSLICE / TPB; ++i) {
        const int p = tid + i * TPB;
        float r0 = rbase[p * 3 + 0], r1 = rbase[p * 3 + 1], r2 = rbase[p * 3 + 2];
        _Float16 h0, l0, h1, l1, h2, l2, rnh, rnl;
        split16(r0, h0, l0);                  // a-side: RAW coords
        split16(r1, h1, l1);
        split16(r2, h2, l2);
        split16(fmaf(r0, r0, fmaf(r1, r1, r2 * r2)), rnh, rnl);
        const int base = (p >> 5) * 64 + (p & 31);            // [tile][hv][row]
        afrag[base]      = (h8){h0, h1, h2, l0, l1, l2, h0, h1};            // k0..7
        afrag[base + 32] = (h8){h2, rnh, rnl, (_Float16)1.0f, (_Float16)1.0f,
                                (_Float16)0.0f, (_Float16)0.0f, (_Float16)0.0f}; // k8..15
    }

    // ---- query B-frags: QT col-tiles per wave, resident in registers ----
    h8 bq[QT];
#pragma unroll
    for (int t = 0; t < QT; ++t) {
        const int qi = qblock * QBLK + (wave * QT + t) * 32 + col;
        const float* qp = q + ((size_t)b * NPTS + qi) * 3;
        float x0 = qp[0], x1 = qp[1], x2 = qp[2];
        _Float16 H0, L0, H1, L1, H2, L2, qnh, qnl;
        split16(-2.0f * x0, H0, L0);          // b-side: -2q, split AFTER scaling
        split16(-2.0f * x1, H1, L1);
        split16(-2.0f * x2, H2, L2);
        split16(fmaf(x0, x0, fmaf(x1, x1, x2 * x2)), qnh, qnl);
        h8 b0 = {H0, H1, H2, H0, H1, H2, L0, L1};                           // k0..7
        h8 b1 = {L2, (_Float16)1.0f, (_Float16)1.0f, qnh, qnl,
                 (_Float16)0.0f, (_Float16)0.0f, (_Float16)0.0f};           // k8..15
        bq[t] = hv ? b1 : b0;
    }
    __syncthreads();

    const f16v zf = {};
    float cm[QT];
#pragma unroll
    for (int t = 0; t < QT; ++t) cm[t] = 3.0e38f;

    // ---- main loop: 1 A-frag read feeds QT MFMAs; min = in-lane tree ----
    for (int mt = 0; mt < MT; ++mt) {
        const h8 ar = afrag[mt * 64 + lane];   // contiguous 16B/lane, conflict-free
#pragma unroll
        for (int t = 0; t < QT; ++t) {
            f16v d = __builtin_amdgcn_mfma_f32_32x32x16_f16(ar, bq[t], zf, 0, 0, 0);
            float u0 = fminf(d[0], d[8]),  u1 = fminf(d[1], d[9]);
            float u2 = fminf(d[2], d[10]), u3 = fminf(d[3], d[11]);
            float u4 = fminf(d[4], d[12]), u5 = fminf(d[5], d[13]);
            float u6 = fminf(d[6], d[14]), u7 = fminf(d[7], d[15]);
            float v0 = fminf(fminf(u0, u1), fminf(u2, u3));    // min3-foldable
            float v1 = fminf(fminf(u4, u5), fminf(u6, u7));
            cm[t] = fminf(cm[t], fminf(v0, v1));
        }
    }

    // ---- epilogue: one xor32 per accumulator, coalesced stores ----
    float* pp = partial + ((size_t)(dir * BATCH + b) * SLICES + slice) * NPTS
                        + qblock * QBLK;
#pragma unroll
    for (int t = 0; t < QT; ++t) {
        cm[t] = fminf(cm[t], __shfl_xor(cm[t], 32, 64));   // hv-partner rows
        if (hv == 0)
            pp[(wave * QT + t) * 32 + col] = cm[t];        // 32 lanes, 128B coalesced
    }
}

__global__ __launch_bounds__(TPB) void chamfer_reduce(const float* __restrict__ partial,
                                                      float* __restrict__ out) {
    const int tid = threadIdx.x;
    const int g   = blockIdx.x * TPB + tid;   // [0, 2*BATCH*NPTS)
    const int db  = g >> 13;                  // (dir*BATCH + b)
    const int n   = g & (NPTS - 1);

    const float* p = partial + (size_t)db * SLICES * NPTS + n;
    float v = 3.0e38f;
#pragma unroll
    for (int s = 0; s < SLICES; ++s)
        v = fminf(v, p[(size_t)s * NPTS]);    // coalesced across threads

    float w = v;
#pragma unroll
    for (int off = 32; off > 0; off >>= 1)
        w += __shfl_down(w, off, 64);
    __shared__ float ss[TPB / 64];
    if ((tid & 63) == 0) ss[tid >> 6] = w;
    __syncthreads();
    if (tid == 0)
        atomicAdd(out, (ss[0] + ss[1] + ss[2] + ss[3]) * (1.0f / (float)(BATCH * NPTS)));
}

extern "C" void kernel_launch(void* const* d_in, const int* in_sizes, int n_in,
                              void* d_out, int out_size, void* d_ws, size_t ws_size,
                              hipStream_t stream) {
    const float* x = (const float*)d_in[0];
    const float* y = (const float*)d_in[1];
    float* out = (float*)d_out;
    float* partial = (float*)d_ws;            // 2*4*8*8192*4 = 2 MB

    hipMemsetAsync(out, 0, sizeof(float), stream);
    chamfer_mfma<<<dim3(QBLKS, BATCH * SLICES, 2), TPB, 0, stream>>>(x, y, partial);
    chamfer_reduce<<<dim3(2 * BATCH * NPTS / TPB), TPB, 0, stream>>>(partial, out);
}

// Round 12
// 86.547 us; speedup vs baseline: 1.0950x; 1.0950x over previous
//
#include <hip/hip_runtime.h>

// ChamferLoss: B=4, N=M=8192, D=3, fp32. Scalar out.
// MFMA split-f16 (validated EXACT r6-r11): A = refs (LDS), B = queries (regs),
// in-lane min tree per 32x32 tile. r11 diagnosis: 41.7us >> ~7us of issue ->
// dependency-stall-bound at ~2 blocks/CU. r12:
//  1) CSLICE 512 (SLICES=16): 2048 blocks = 8/CU submitted, LDS 16KB
//     (~10 blocks/CU capacity) -> ~4x resident waves to hide MFMA->tree chains.
//  2) min3-shaped tree: 8 v_min3_f32 per MFMA (was 16 v_min), depth 3.

#define BATCH   4
#define NPTS    8192
#define TPB     256
#define CSLICE  512                  // ref points per block (LDS slice)
#define QT      4                    // query tiles (32 cols) per wave
#define QBLK    (4 * QT * 32)        // 512 queries per block
#define MT      (CSLICE / 32)        // 16 ref tiles per slice
#define SLICES  (NPTS / CSLICE)      // 16
#define QBLKS   (NPTS / QBLK)        // 16

typedef _Float16 h8   __attribute__((ext_vector_type(8)));
typedef float    f16v __attribute__((ext_vector_type(16)));

__device__ __forceinline__ void split16(float v, _Float16& hi, _Float16& lo) {
    hi = (_Float16)v;
    lo = (_Float16)(v - (float)hi);
}

__global__ __launch_bounds__(TPB) void chamfer_mfma(const float* __restrict__ xg,
                                                    const float* __restrict__ yg,
                                                    float* __restrict__ partial) {
    __shared__ h8 afrag[CSLICE * 2];          // 16 KB, de-interleaved (conflict-free)

    const int tid    = threadIdx.x;
    const int qblock = blockIdx.x;            // [0,16)
    const int slice  = blockIdx.y & (SLICES - 1);
    const int b      = blockIdx.y >> 4;       // SLICES == 16
    const int dir    = blockIdx.z;
    const int lane   = tid & 63, wave = tid >> 6;
    const int col    = lane & 31, hv = lane >> 5;

    const float* q = dir ? yg : xg;           // query side (cols, register B-frags)
    const float* r = dir ? xg : yg;           // reference side (rows, LDS A-frags)

    // ---- stage ref A-frags: 2 points per thread, de-interleaved layout ----
    const float* rbase = r + ((size_t)b * NPTS + slice * CSLICE) * 3;
#pragma unroll
    for (int i = 0; i < CSLICE / TPB; ++i) {
        const int p = tid + i * TPB;
        float r0 = rbase[p * 3 + 0], r1 = rbase[p * 3 + 1], r2 = rbase[p * 3 + 2];
        _Float16 h0, l0, h1, l1, h2, l2, rnh, rnl;
        split16(r0, h0, l0);                  // a-side: RAW coords
        split16(r1, h1, l1);
        split16(r2, h2, l2);
        split16(fmaf(r0, r0, fmaf(r1, r1, r2 * r2)), rnh, rnl);
        const int base = (p >> 5) * 64 + (p & 31);            // [tile][hv][row]
        afrag[base]      = (h8){h0, h1, h2, l0, l1, l2, h0, h1};            // k0..7
        afrag[base + 32] = (h8){h2, rnh, rnl, (_Float16)1.0f, (_Float16)1.0f,
                                (_Float16)0.0f, (_Float16)0.0f, (_Float16)0.0f}; // k8..15
    }

    // ---- query B-frags: QT col-tiles per wave, resident in registers ----
    h8 bq[QT];
#pragma unroll
    for (int t = 0; t < QT; ++t) {
        const int qi = qblock * QBLK + (wave * QT + t) * 32 + col;
        const float* qp = q + ((size_t)b * NPTS + qi) * 3;
        float x0 = qp[0], x1 = qp[1], x2 = qp[2];
        _Float16 H0, L0, H1, L1, H2, L2, qnh, qnl;
        split16(-2.0f * x0, H0, L0);          // b-side: -2q, split AFTER scaling
        split16(-2.0f * x1, H1, L1);
        split16(-2.0f * x2, H2, L2);
        split16(fmaf(x0, x0, fmaf(x1, x1, x2 * x2)), qnh, qnl);
        h8 b0 = {H0, H1, H2, H0, H1, H2, L0, L1};                           // k0..7
        h8 b1 = {L2, (_Float16)1.0f, (_Float16)1.0f, qnh, qnl,
                 (_Float16)0.0f, (_Float16)0.0f, (_Float16)0.0f};           // k8..15
        bq[t] = hv ? b1 : b0;
    }
    __syncthreads();

    const f16v zf = {};
    float cm[QT];
#pragma unroll
    for (int t = 0; t < QT; ++t) cm[t] = 3.0e38f;

    // ---- main loop: 1 A-frag read feeds QT MFMAs; min3-shaped in-lane tree ----
    for (int mt = 0; mt < MT; ++mt) {
        const h8 ar = afrag[mt * 64 + lane];   // contiguous 16B/lane, conflict-free
#pragma unroll
        for (int t = 0; t < QT; ++t) {
            f16v d = __builtin_amdgcn_mfma_f32_32x32x16_f16(ar, bq[t], zf, 0, 0, 0);
            // 8 v_min3_f32 (triples fold), depth 3
            float a0 = fminf(fminf(d[0],  d[1]),  d[2]);
            float a1 = fminf(fminf(d[3],  d[4]),  d[5]);
            float a2 = fminf(fminf(d[6],  d[7]),  d[8]);
            float a3 = fminf(fminf(d[9],  d[10]), d[11]);
            float a4 = fminf(fminf(d[12], d[13]), d[14]);
            float b0 = fminf(fminf(a0, a1), a2);
            float b1 = fminf(fminf(a3, a4), d[15]);
            cm[t] = fminf(fminf(cm[t], b0), b1);
        }
    }

    // ---- epilogue: one xor32 per accumulator, coalesced stores ----
    float* pp = partial + ((size_t)(dir * BATCH + b) * SLICES + slice) * NPTS
                        + qblock * QBLK;
#pragma unroll
    for (int t = 0; t < QT; ++t) {
        cm[t] = fminf(cm[t], __shfl_xor(cm[t], 32, 64));   // hv-partner rows
        if (hv == 0)
            pp[(wave * QT + t) * 32 + col] = cm[t];        // 32 lanes, 128B coalesced
    }
}

__global__ __launch_bounds__(TPB) void chamfer_reduce(const float* __restrict__ partial,
                                                      float* __restrict__ out) {
    const int tid = threadIdx.x;
    const int g   = blockIdx.x * TPB + tid;   // [0, 2*BATCH*NPTS)
    const int db  = g >> 13;                  // (dir*BATCH + b)
    const int n   = g & (NPTS - 1);

    const float* p = partial + (size_t)db * SLICES * NPTS + n;
    float v = 3.0e38f;
#pragma unroll
    for (int s = 0; s < SLICES; ++s)
        v = fminf(v, p[(size_t)s * NPTS]);    // coalesced across threads

    float w = v;
#pragma unroll
    for (int off = 32; off > 0; off >>= 1)
        w += __shfl_down(w, off, 64);
    __shared__ float ss[TPB / 64];
    if ((tid & 63) == 0) ss[tid >> 6] = w;
    __syncthreads();
    if (tid == 0)
        atomicAdd(out, (ss[0] + ss[1] + ss[2] + ss[3]) * (1.0f / (float)(BATCH * NPTS)));
}

extern "C" void kernel_launch(void* const* d_in, const int* in_sizes, int n_in,
                              void* d_out, int out_size, void* d_ws, size_t ws_size,
                              hipStream_t stream) {
    const float* x = (const float*)d_in[0];
    const float* y = (const float*)d_in[1];
    float* out = (float*)d_out;
    float* partial = (float*)d_ws;            // 2*4*16*8192*4 = 4 MB

    hipMemsetAsync(out, 0, sizeof(float), stream);
    chamfer_mfma<<<dim3(QBLKS, BATCH * SLICES, 2), TPB, 0, stream>>>(x, y, partial);
    chamfer_reduce<<<dim3(2 * BATCH * NPTS / TPB), TPB, 0, stream>>>(partial, out);
}

// Round 13
// 79.676 us; speedup vs baseline: 1.1894x; 1.0862x over previous
//
#include <hip/hip_runtime.h>

// ChamferLoss: B=4, N=M=8192, D=3, fp32. Scalar out.
// MFMA split-f16 (validated EXACT r6-r12): A = refs (LDS), B = queries (regs),
// in-lane min tree per 32x32 tile. r12 diagnosis: VGPR_Count=44 -> LLVM put
// MFMA dest + zero-C in AGPRs; every d[i] read costs v_accvgpr_read on the
// contended VALU pipe (~16 extra VALU/MFMA, the 2-3x VALU inflation seen
// since r8). r13: inline-asm MFMA with "=v" dest (gfx950 unified RF: MFMA
// can write VGPRs directly), s_nop 7 x2 in-asm for the MFMA->VALU hazard
// (scalar-slot idle, not VALU issue), 8-deep min3 tree.

#define BATCH   4
#define NPTS    8192
#define TPB     256
#define CSLICE  512                  // ref points per block (LDS slice)
#define QT      4                    // query tiles (32 cols) per wave
#define QBLK    (4 * QT * 32)        // 512 queries per block
#define MT      (CSLICE / 32)        // 16 ref tiles per slice
#define SLICES  (NPTS / CSLICE)      // 16
#define QBLKS   (NPTS / QBLK)        // 16

typedef _Float16 h8   __attribute__((ext_vector_type(8)));
typedef float    f16v __attribute__((ext_vector_type(16)));

__device__ __forceinline__ void split16(float v, _Float16& hi, _Float16& lo) {
    hi = (_Float16)v;
    lo = (_Float16)(v - (float)hi);
}

__global__ __launch_bounds__(TPB) void chamfer_mfma(const float* __restrict__ xg,
                                                    const float* __restrict__ yg,
                                                    float* __restrict__ partial) {
    __shared__ h8 afrag[CSLICE * 2];          // 16 KB, de-interleaved (conflict-free)

    const int tid    = threadIdx.x;
    const int qblock = blockIdx.x;            // [0,16)
    const int slice  = blockIdx.y & (SLICES - 1);
    const int b      = blockIdx.y >> 4;       // SLICES == 16
    const int dir    = blockIdx.z;
    const int lane   = tid & 63, wave = tid >> 6;
    const int col    = lane & 31, hv = lane >> 5;

    const float* q = dir ? yg : xg;           // query side (cols, register B-frags)
    const float* r = dir ? xg : yg;           // reference side (rows, LDS A-frags)

    // ---- stage ref A-frags: 2 points per thread, de-interleaved layout ----
    const float* rbase = r + ((size_t)b * NPTS + slice * CSLICE) * 3;
#pragma unroll
    for (int i = 0; i < CSLICE / TPB; ++i) {
        const int p = tid + i * TPB;
        float r0 = rbase[p * 3 + 0], r1 = rbase[p * 3 + 1], r2 = rbase[p * 3 + 2];
        _Float16 h0, l0, h1, l1, h2, l2, rnh, rnl;
        split16(r0, h0, l0);                  // a-side: RAW coords
        split16(r1, h1, l1);
        split16(r2, h2, l2);
        split16(fmaf(r0, r0, fmaf(r1, r1, r2 * r2)), rnh, rnl);
        const int base = (p >> 5) * 64 + (p & 31);            // [tile][hv][row]
        afrag[base]      = (h8){h0, h1, h2, l0, l1, l2, h0, h1};            // k0..7
        afrag[base + 32] = (h8){h2, rnh, rnl, (_Float16)1.0f, (_Float16)1.0f,
                                (_Float16)0.0f, (_Float16)0.0f, (_Float16)0.0f}; // k8..15
    }

    // ---- query B-frags: QT col-tiles per wave, resident in registers ----
    h8 bq[QT];
#pragma unroll
    for (int t = 0; t < QT; ++t) {
        const int qi = qblock * QBLK + (wave * QT + t) * 32 + col;
        const float* qp = q + ((size_t)b * NPTS + qi) * 3;
        float x0 = qp[0], x1 = qp[1], x2 = qp[2];
        _Float16 H0, L0, H1, L1, H2, L2, qnh, qnl;
        split16(-2.0f * x0, H0, L0);          // b-side: -2q, split AFTER scaling
        split16(-2.0f * x1, H1, L1);
        split16(-2.0f * x2, H2, L2);
        split16(fmaf(x0, x0, fmaf(x1, x1, x2 * x2)), qnh, qnl);
        h8 b0 = {H0, H1, H2, H0, H1, H2, L0, L1};                           // k0..7
        h8 b1 = {L2, (_Float16)1.0f, (_Float16)1.0f, qnh, qnl,
                 (_Float16)0.0f, (_Float16)0.0f, (_Float16)0.0f};           // k8..15
        bq[t] = hv ? b1 : b0;
    }
    __syncthreads();

    f16v zf;                                  // zero C tuple, VGPR-resident
#pragma unroll
    for (int i = 0; i < 16; ++i) zf[i] = 0.0f;
    float cm[QT];
#pragma unroll
    for (int t = 0; t < QT; ++t) cm[t] = 3.0e38f;

    // ---- main loop: 1 A-frag read feeds QT MFMAs; VGPR dest, min3 tree ----
    for (int mt = 0; mt < MT; ++mt) {
        const h8 ar = afrag[mt * 64 + lane];   // contiguous 16B/lane, conflict-free
#pragma unroll
        for (int t = 0; t < QT; ++t) {
            f16v d;
            // VGPR destination (no AGPR moves); s_nops cover MFMA->VALU hazard
            asm("v_mfma_f32_32x32x16_f16 %0, %1, %2, %3\n\t"
                "s_nop 7\n\t"
                "s_nop 7"
                : "=v"(d) : "v"(ar), "v"(bq[t]), "v"(zf));
            // 8-op min3 tree: 16 -> 1
            float g0 = fminf(fminf(d[0],  d[1]),  d[2]);
            float g1 = fminf(fminf(d[3],  d[4]),  d[5]);
            float g2 = fminf(fminf(d[6],  d[7]),  d[8]);
            float g3 = fminf(fminf(d[9],  d[10]), d[11]);
            float g4 = fminf(fminf(d[12], d[13]), d[14]);
            float h0 = fminf(fminf(g0, g1), d[15]);
            float h1 = fminf(fminf(g2, g3), g4);
            cm[t] = fminf(fminf(cm[t], h0), h1);
        }
    }

    // ---- epilogue: one xor32 per accumulator, coalesced stores ----
    float* pp = partial + ((size_t)(dir * BATCH + b) * SLICES + slice) * NPTS
                        + qblock * QBLK;
#pragma unroll
    for (int t = 0; t < QT; ++t) {
        cm[t] = fminf(cm[t], __shfl_xor(cm[t], 32, 64));   // hv-partner rows
        if (hv == 0)
            pp[(wave * QT + t) * 32 + col] = cm[t];        // 32 lanes, 128B coalesced
    }
}

__global__ __launch_bounds__(TPB) void chamfer_reduce(const float* __restrict__ partial,
                                                      float* __restrict__ out) {
    const int tid = threadIdx.x;
    const int g   = blockIdx.x * TPB + tid;   // [0, 2*BATCH*NPTS)
    const int db  = g >> 13;                  // (dir*BATCH + b)
    const int n   = g & (NPTS - 1);

    const float* p = partial + (size_t)db * SLICES * NPTS + n;
    float v = 3.0e38f;
#pragma unroll
    for (int s = 0; s < SLICES; ++s)
        v = fminf(v, p[(size_t)s * NPTS]);    // coalesced across threads

    float w = v;
#pragma unroll
    for (int off = 32; off > 0; off >>= 1)
        w += __shfl_down(w, off, 64);
    __shared__ float ss[TPB / 64];
    if ((tid & 63) == 0) ss[tid >> 6] = w;
    __syncthreads();
    if (tid == 0)
        atomicAdd(out, (ss[0] + ss[1] + ss[2] + ss[3]) * (1.0f / (float)(BATCH * NPTS)));
}

extern "C" void kernel_launch(void* const* d_in, const int* in_sizes, int n_in,
                              void* d_out, int out_size, void* d_ws, size_t ws_size,
                              hipStream_t stream) {
    const float* x = (const float*)d_in[0];
    const float* y = (const float*)d_in[1];
    float* out = (float*)d_out;
    float* partial = (float*)d_ws;            // 2*4*16*8192*4 = 4 MB

    hipMemsetAsync(out, 0, sizeof(float), stream);
    chamfer_mfma<<<dim3(QBLKS, BATCH * SLICES, 2), TPB, 0, stream>>>(x, y, partial);
    chamfer_reduce<<<dim3(2 * BATCH * NPTS / TPB), TPB, 0, stream>>>(partial, out);
}

// Round 14
// 78.252 us; speedup vs baseline: 1.2111x; 1.0182x over previous
//
#include <hip/hip_runtime.h>

// ChamferLoss: B=4, N=M=8192, D=3, fp32. Scalar out.
// MFMA split-f16 (validated EXACT r6-r13): A = refs (LDS), B = queries (regs),
// in-lane min3 tree per 32x32 tile, VGPR-dest asm MFMA (r13: killed the
// v_accvgpr_read tax, VGPR_Count 44 -> ~100).
// r14: ONE asm block issues all QT=4 MFMAs back-to-back with a SINGLE
// 2x s_nop 7 tail (r13 proved 16 cycles suffices per-MFMA; last MFMA of the
// group gets exactly that, earlier ones more). Nop overhead per iteration:
// 64 -> 16 cycles. C operand = inline constant 0 (drops the zf tuple).

#define BATCH   4
#define NPTS    8192
#define TPB     256
#define CSLICE  512                  // ref points per block (LDS slice)
#define QT      4                    // query tiles (32 cols) per wave
#define QBLK    (4 * QT * 32)        // 512 queries per block
#define MT      (CSLICE / 32)        // 16 ref tiles per slice
#define SLICES  (NPTS / CSLICE)      // 16
#define QBLKS   (NPTS / QBLK)        // 16

typedef _Float16 h8   __attribute__((ext_vector_type(8)));
typedef float    f16v __attribute__((ext_vector_type(16)));

__device__ __forceinline__ void split16(float v, _Float16& hi, _Float16& lo) {
    hi = (_Float16)v;
    lo = (_Float16)(v - (float)hi);
}

__global__ __launch_bounds__(TPB) void chamfer_mfma(const float* __restrict__ xg,
                                                    const float* __restrict__ yg,
                                                    float* __restrict__ partial) {
    __shared__ h8 afrag[CSLICE * 2];          // 16 KB, de-interleaved (conflict-free)

    const int tid    = threadIdx.x;
    const int qblock = blockIdx.x;            // [0,16)
    const int slice  = blockIdx.y & (SLICES - 1);
    const int b      = blockIdx.y >> 4;       // SLICES == 16
    const int dir    = blockIdx.z;
    const int lane   = tid & 63, wave = tid >> 6;
    const int col    = lane & 31, hv = lane >> 5;

    const float* q = dir ? yg : xg;           // query side (cols, register B-frags)
    const float* r = dir ? xg : yg;           // reference side (rows, LDS A-frags)

    // ---- stage ref A-frags: 2 points per thread, de-interleaved layout ----
    const float* rbase = r + ((size_t)b * NPTS + slice * CSLICE) * 3;
#pragma unroll
    for (int i = 0; i < CSLICE / TPB; ++i) {
        const int p = tid + i * TPB;
        float r0 = rbase[p * 3 + 0], r1 = rbase[p * 3 + 1], r2 = rbase[p * 3 + 2];
        _Float16 h0, l0, h1, l1, h2, l2, rnh, rnl;
        split16(r0, h0, l0);                  // a-side: RAW coords
        split16(r1, h1, l1);
        split16(r2, h2, l2);
        split16(fmaf(r0, r0, fmaf(r1, r1, r2 * r2)), rnh, rnl);
        const int base = (p >> 5) * 64 + (p & 31);            // [tile][hv][row]
        afrag[base]      = (h8){h0, h1, h2, l0, l1, l2, h0, h1};            // k0..7
        afrag[base + 32] = (h8){h2, rnh, rnl, (_Float16)1.0f, (_Float16)1.0f,
                                (_Float16)0.0f, (_Float16)0.0f, (_Float16)0.0f}; // k8..15
    }

    // ---- query B-frags: QT col-tiles per wave, resident in registers ----
    h8 bq[QT];
#pragma unroll
    for (int t = 0; t < QT; ++t) {
        const int qi = qblock * QBLK + (wave * QT + t) * 32 + col;
        const float* qp = q + ((size_t)b * NPTS + qi) * 3;
        float x0 = qp[0], x1 = qp[1], x2 = qp[2];
        _Float16 H0, L0, H1, L1, H2, L2, qnh, qnl;
        split16(-2.0f * x0, H0, L0);          // b-side: -2q, split AFTER scaling
        split16(-2.0f * x1, H1, L1);
        split16(-2.0f * x2, H2, L2);
        split16(fmaf(x0, x0, fmaf(x1, x1, x2 * x2)), qnh, qnl);
        h8 b0 = {H0, H1, H2, H0, H1, H2, L0, L1};                           // k0..7
        h8 b1 = {L2, (_Float16)1.0f, (_Float16)1.0f, qnh, qnl,
                 (_Float16)0.0f, (_Float16)0.0f, (_Float16)0.0f};           // k8..15
        bq[t] = hv ? b1 : b0;
    }
    __syncthreads();

    float cm[QT];
#pragma unroll
    for (int t = 0; t < QT; ++t) cm[t] = 3.0e38f;

    // ---- main loop: 1 A-frag read -> 4 back-to-back MFMAs -> 4 min3 trees ----
    for (int mt = 0; mt < MT; ++mt) {
        const h8 ar = afrag[mt * 64 + lane];   // contiguous 16B/lane, conflict-free
        f16v d0, d1, d2, d3;
        // Back-to-back group; single hazard tail (16 cyc, r13-proven per-MFMA
        // sufficiency -> last MFMA gets >= requirement, earlier ones more).
        asm("v_mfma_f32_32x32x16_f16 %0, %4, %5, 0\n\t"
            "v_mfma_f32_32x32x16_f16 %1, %4, %6, 0\n\t"
            "v_mfma_f32_32x32x16_f16 %2, %4, %7, 0\n\t"
            "v_mfma_f32_32x32x16_f16 %3, %4, %8, 0\n\t"
            "s_nop 7\n\t"
            "s_nop 7"
            : "=v"(d0), "=v"(d1), "=v"(d2), "=v"(d3)
            : "v"(ar), "v"(bq[0]), "v"(bq[1]), "v"(bq[2]), "v"(bq[3]));

        // 4 independent 8-min3 trees (interleave for ILP)
#pragma unroll
        for (int t = 0; t < QT; ++t) {
            const f16v& d = (t == 0) ? d0 : (t == 1) ? d1 : (t == 2) ? d2 : d3;
            float g0 = fminf(fminf(d[0],  d[1]),  d[2]);
            float g1 = fminf(fminf(d[3],  d[4]),  d[5]);
            float g2 = fminf(fminf(d[6],  d[7]),  d[8]);
            float g3 = fminf(fminf(d[9],  d[10]), d[11]);
            float g4 = fminf(fminf(d[12], d[13]), d[14]);
            float h0 = fminf(fminf(g0, g1), d[15]);
            float h1 = fminf(fminf(g2, g3), g4);
            cm[t] = fminf(fminf(cm[t], h0), h1);
        }
    }

    // ---- epilogue: one xor32 per accumulator, coalesced stores ----
    float* pp = partial + ((size_t)(dir * BATCH + b) * SLICES + slice) * NPTS
                        + qblock * QBLK;
#pragma unroll
    for (int t = 0; t < QT; ++t) {
        cm[t] = fminf(cm[t], __shfl_xor(cm[t], 32, 64));   // hv-partner rows
        if (hv == 0)
            pp[(wave * QT + t) * 32 + col] = cm[t];        // 32 lanes, 128B coalesced
    }
}

__global__ __launch_bounds__(TPB) void chamfer_reduce(const float* __restrict__ partial,
                                                      float* __restrict__ out) {
    const int tid = threadIdx.x;
    const int g   = blockIdx.x * TPB + tid;   // [0, 2*BATCH*NPTS)
    const int db  = g >> 13;                  // (dir*BATCH + b)
    const int n   = g & (NPTS - 1);

    const float* p = partial + (size_t)db * SLICES * NPTS + n;
    float v = 3.0e38f;
#pragma unroll
    for (int s = 0; s < SLICES; ++s)
        v = fminf(v, p[(size_t)s * NPTS]);    // coalesced across threads

    float w = v;
#pragma unroll
    for (int off = 32; off > 0; off >>= 1)
        w += __shfl_down(w, off, 64);
    __shared__ float ss[TPB / 64];
    if ((tid & 63) == 0) ss[tid >> 6] = w;
    __syncthreads();
    if (tid == 0)
        atomicAdd(out, (ss[0] + ss[1] + ss[2] + ss[3]) * (1.0f / (float)(BATCH * NPTS)));
}

extern "C" void kernel_launch(void* const* d_in, const int* in_sizes, int n_in,
                              void* d_out, int out_size, void* d_ws, size_t ws_size,
                              hipStream_t stream) {
    const float* x = (const float*)d_in[0];
    const float* y = (const float*)d_in[1];
    float* out = (float*)d_out;
    float* partial = (float*)d_ws;            // 2*4*16*8192*4 = 4 MB

    hipMemsetAsync(out, 0, sizeof(float), stream);
    chamfer_mfma<<<dim3(QBLKS, BATCH * SLICES, 2), TPB, 0, stream>>>(x, y, partial);
    chamfer_reduce<<<dim3(2 * BATCH * NPTS / TPB), TPB, 0, stream>>>(partial, out);
}

// Round 15
// 77.620 us; speedup vs baseline: 1.2209x; 1.0081x over previous
//
#include <hip/hip_runtime.h>

// ChamferLoss: B=4, N=M=8192, D=3, fp32. Scalar out.
// MFMA split-f16 (validated EXACT r6-r14): A = refs (LDS), B = queries (regs),
// in-lane min3 tree, VGPR-dest asm MFMA (r13), grouped hazard tail (r14).
// r15: (1) MFMA group split 2+2 with trees between -> max live d = 32 regs
// (target VGPR <= 64 band = 8 waves/SIMD per m69 halving points; no loss if
// we land in the 65-128 band). (2) memset dispatch deleted: out zeroed by
// every main block (benign identical-value store, r1-r4-validated).

#define BATCH   4
#define NPTS    8192
#define TPB     256
#define CSLICE  512                  // ref points per block (LDS slice)
#define QT      4                    // query tiles (32 cols) per wave
#define QBLK    (4 * QT * 32)        // 512 queries per block
#define MT      (CSLICE / 32)        // 16 ref tiles per slice
#define SLICES  (NPTS / CSLICE)      // 16
#define QBLKS   (NPTS / QBLK)        // 16

typedef _Float16 h8   __attribute__((ext_vector_type(8)));
typedef float    f16v __attribute__((ext_vector_type(16)));

__device__ __forceinline__ void split16(float v, _Float16& hi, _Float16& lo) {
    hi = (_Float16)v;
    lo = (_Float16)(v - (float)hi);
}

__device__ __forceinline__ float tree16(const f16v& d) {
    float g0 = fminf(fminf(d[0],  d[1]),  d[2]);
    float g1 = fminf(fminf(d[3],  d[4]),  d[5]);
    float g2 = fminf(fminf(d[6],  d[7]),  d[8]);
    float g3 = fminf(fminf(d[9],  d[10]), d[11]);
    float g4 = fminf(fminf(d[12], d[13]), d[14]);
    float h0 = fminf(fminf(g0, g1), d[15]);
    float h1 = fminf(fminf(g2, g3), g4);
    return fminf(h0, h1);
}

__global__ __launch_bounds__(TPB) void chamfer_mfma(const float* __restrict__ xg,
                                                    const float* __restrict__ yg,
                                                    float* __restrict__ partial,
                                                    float* __restrict__ out) {
    __shared__ h8 afrag[CSLICE * 2];          // 16 KB, de-interleaved (conflict-free)

    const int tid    = threadIdx.x;
    const int qblock = blockIdx.x;            // [0,16)
    const int slice  = blockIdx.y & (SLICES - 1);
    const int b      = blockIdx.y >> 4;       // SLICES == 16
    const int dir    = blockIdx.z;
    const int lane   = tid & 63, wave = tid >> 6;
    const int col    = lane & 31, hv = lane >> 5;

    if (tid == 0) out[0] = 0.0f;              // benign identical-value race;
                                              // reduce runs after via stream order
    const float* q = dir ? yg : xg;           // query side (cols, register B-frags)
    const float* r = dir ? xg : yg;           // reference side (rows, LDS A-frags)

    // ---- stage ref A-frags: 2 points per thread, de-interleaved layout ----
    const float* rbase = r + ((size_t)b * NPTS + slice * CSLICE) * 3;
#pragma unroll
    for (int i = 0; i < CSLICE / TPB; ++i) {
        const int p = tid + i * TPB;
        float r0 = rbase[p * 3 + 0], r1 = rbase[p * 3 + 1], r2 = rbase[p * 3 + 2];
        _Float16 h0, l0, h1, l1, h2, l2, rnh, rnl;
        split16(r0, h0, l0);                  // a-side: RAW coords
        split16(r1, h1, l1);
        split16(r2, h2, l2);
        split16(fmaf(r0, r0, fmaf(r1, r1, r2 * r2)), rnh, rnl);
        const int base = (p >> 5) * 64 + (p & 31);            // [tile][hv][row]
        afrag[base]      = (h8){h0, h1, h2, l0, l1, l2, h0, h1};            // k0..7
        afrag[base + 32] = (h8){h2, rnh, rnl, (_Float16)1.0f, (_Float16)1.0f,
                                (_Float16)0.0f, (_Float16)0.0f, (_Float16)0.0f}; // k8..15
    }

    // ---- query B-frags: QT col-tiles per wave, resident in registers ----
    h8 bq[QT];
#pragma unroll
    for (int t = 0; t < QT; ++t) {
        const int qi = qblock * QBLK + (wave * QT + t) * 32 + col;
        const float* qp = q + ((size_t)b * NPTS + qi) * 3;
        float x0 = qp[0], x1 = qp[1], x2 = qp[2];
        _Float16 H0, L0, H1, L1, H2, L2, qnh, qnl;
        split16(-2.0f * x0, H0, L0);          // b-side: -2q, split AFTER scaling
        split16(-2.0f * x1, H1, L1);
        split16(-2.0f * x2, H2, L2);
        split16(fmaf(x0, x0, fmaf(x1, x1, x2 * x2)), qnh, qnl);
        h8 b0 = {H0, H1, H2, H0, H1, H2, L0, L1};                           // k0..7
        h8 b1 = {L2, (_Float16)1.0f, (_Float16)1.0f, qnh, qnl,
                 (_Float16)0.0f, (_Float16)0.0f, (_Float16)0.0f};           // k8..15
        bq[t] = hv ? b1 : b0;
    }
    __syncthreads();

    float cm[QT];
#pragma unroll
    for (int t = 0; t < QT; ++t) cm[t] = 3.0e38f;

    // ---- main loop: 1 A-frag read -> 2x (2 MFMAs + 2 trees); d-pair live only ----
    for (int mt = 0; mt < MT; ++mt) {
        const h8 ar = afrag[mt * 64 + lane];   // contiguous 16B/lane, conflict-free
        f16v d0, d1;
        asm("v_mfma_f32_32x32x16_f16 %0, %2, %3, 0\n\t"
            "v_mfma_f32_32x32x16_f16 %1, %2, %4, 0\n\t"
            "s_nop 7\n\t"
            "s_nop 7"
            : "=v"(d0), "=v"(d1)
            : "v"(ar), "v"(bq[0]), "v"(bq[1]));
        cm[0] = fminf(cm[0], tree16(d0));
        cm[1] = fminf(cm[1], tree16(d1));

        f16v d2, d3;
        asm("v_mfma_f32_32x32x16_f16 %0, %2, %3, 0\n\t"
            "v_mfma_f32_32x32x16_f16 %1, %2, %4, 0\n\t"
            "s_nop 7\n\t"
            "s_nop 7"
            : "=v"(d2), "=v"(d3)
            : "v"(ar), "v"(bq[2]), "v"(bq[3]));
        cm[2] = fminf(cm[2], tree16(d2));
        cm[3] = fminf(cm[3], tree16(d3));
    }

    // ---- epilogue: one xor32 per accumulator, coalesced stores ----
    float* pp = partial + ((size_t)(dir * BATCH + b) * SLICES + slice) * NPTS
                        + qblock * QBLK;
#pragma unroll
    for (int t = 0; t < QT; ++t) {
        cm[t] = fminf(cm[t], __shfl_xor(cm[t], 32, 64));   // hv-partner rows
        if (hv == 0)
            pp[(wave * QT + t) * 32 + col] = cm[t];        // 32 lanes, 128B coalesced
    }
}

__global__ __launch_bounds__(TPB) void chamfer_reduce(const float* __restrict__ partial,
                                                      float* __restrict__ out) {
    const int tid = threadIdx.x;
    const int g   = blockIdx.x * TPB + tid;   // [0, 2*BATCH*NPTS)
    const int db  = g >> 13;                  // (dir*BATCH + b)
    const int n   = g & (NPTS - 1);

    const float* p = partial + (size_t)db * SLICES * NPTS + n;
    float v = 3.0e38f;
#pragma unroll
    for (int s = 0; s < SLICES; ++s)
        v = fminf(v, p[(size_t)s * NPTS]);    // coalesced across threads

    float w = v;
#pragma unroll
    for (int off = 32; off > 0; off >>= 1)
        w += __shfl_down(w, off, 64);
    __shared__ float ss[TPB / 64];
    if ((tid & 63) == 0) ss[tid >> 6] = w;
    __syncthreads();
    if (tid == 0)
        atomicAdd(out, (ss[0] + ss[1] + ss[2] + ss[3]) * (1.0f / (float)(BATCH * NPTS)));
}

extern "C" void kernel_launch(void* const* d_in, const int* in_sizes, int n_in,
                              void* d_out, int out_size, void* d_ws, size_t ws_size,
                              hipStream_t stream) {
    const float* x = (const float*)d_in[0];
    const float* y = (const float*)d_in[1];
    float* out = (float*)d_out;
    float* partial = (float*)d_ws;            // 2*4*16*8192*4 = 4 MB

    chamfer_mfma<<<dim3(QBLKS, BATCH * SLICES, 2), TPB, 0, stream>>>(x, y, partial, out);
    chamfer_reduce<<<dim3(2 * BATCH * NPTS / TPB), TPB, 0, stream>>>(partial, out);
}

// Round 16
// 77.528 us; speedup vs baseline: 1.2224x; 1.0012x over previous
//
#include <hip/hip_runtime.h>

// ChamferLoss: B=4, N=M=8192, D=3, fp32. Scalar out.
// MFMA split-f16 (validated EXACT r6-r15): A = refs (LDS), B = queries (regs),
// in-lane min3 tree, VGPR-dest asm MFMA (r13), 2+2 grouped hazard tail (r15).
// r16: force the <=64-VGPR band via __launch_bounds__(256, 8) (= 8 blocks/CU
// for 256-thread blocks) -> 8 waves/SIMD, 2x latency hiding for the
// MFMA->tree dependency chains. Live-set audit: bq(16)+d-pair(32)+ar(4)+
// cm(4)+addr ~ 60-70 regs, right at the boundary. Failure mode = spill
// (r9 signature in FETCH/WRITE) -> revert to r15.

#define BATCH   4
#define NPTS    8192
#define TPB     256
#define CSLICE  512                  // ref points per block (LDS slice)
#define QT      4                    // query tiles (32 cols) per wave
#define QBLK    (4 * QT * 32)        // 512 queries per block
#define MT      (CSLICE / 32)        // 16 ref tiles per slice
#define SLICES  (NPTS / CSLICE)      // 16
#define QBLKS   (NPTS / QBLK)        // 16

typedef _Float16 h8   __attribute__((ext_vector_type(8)));
typedef float    f16v __attribute__((ext_vector_type(16)));

__device__ __forceinline__ void split16(float v, _Float16& hi, _Float16& lo) {
    hi = (_Float16)v;
    lo = (_Float16)(v - (float)hi);
}

__device__ __forceinline__ float tree16(const f16v& d) {
    float g0 = fminf(fminf(d[0],  d[1]),  d[2]);
    float g1 = fminf(fminf(d[3],  d[4]),  d[5]);
    float g2 = fminf(fminf(d[6],  d[7]),  d[8]);
    float g3 = fminf(fminf(d[9],  d[10]), d[11]);
    float g4 = fminf(fminf(d[12], d[13]), d[14]);
    float h0 = fminf(fminf(g0, g1), d[15]);
    float h1 = fminf(fminf(g2, g3), g4);
    return fminf(h0, h1);
}

__global__ __launch_bounds__(TPB, 8) void chamfer_mfma(const float* __restrict__ xg,
                                                       const float* __restrict__ yg,
                                                       float* __restrict__ partial,
                                                       float* __restrict__ out) {
    __shared__ h8 afrag[CSLICE * 2];          // 16 KB, de-interleaved (conflict-free)

    const int tid    = threadIdx.x;
    const int qblock = blockIdx.x;            // [0,16)
    const int slice  = blockIdx.y & (SLICES - 1);
    const int b      = blockIdx.y >> 4;       // SLICES == 16
    const int dir    = blockIdx.z;
    const int lane   = tid & 63, wave = tid >> 6;
    const int col    = lane & 31, hv = lane >> 5;

    if (tid == 0) out[0] = 0.0f;              // benign identical-value race;
                                              // reduce runs after via stream order
    const float* q = dir ? yg : xg;           // query side (cols, register B-frags)
    const float* r = dir ? xg : yg;           // reference side (rows, LDS A-frags)

    // ---- stage ref A-frags: 2 points per thread, de-interleaved layout ----
    const float* rbase = r + ((size_t)b * NPTS + slice * CSLICE) * 3;
#pragma unroll
    for (int i = 0; i < CSLICE / TPB; ++i) {
        const int p = tid + i * TPB;
        float r0 = rbase[p * 3 + 0], r1 = rbase[p * 3 + 1], r2 = rbase[p * 3 + 2];
        _Float16 h0, l0, h1, l1, h2, l2, rnh, rnl;
        split16(r0, h0, l0);                  // a-side: RAW coords
        split16(r1, h1, l1);
        split16(r2, h2, l2);
        split16(fmaf(r0, r0, fmaf(r1, r1, r2 * r2)), rnh, rnl);
        const int base = (p >> 5) * 64 + (p & 31);            // [tile][hv][row]
        afrag[base]      = (h8){h0, h1, h2, l0, l1, l2, h0, h1};            // k0..7
        afrag[base + 32] = (h8){h2, rnh, rnl, (_Float16)1.0f, (_Float16)1.0f,
                                (_Float16)0.0f, (_Float16)0.0f, (_Float16)0.0f}; // k8..15
    }

    // ---- query B-frags: QT col-tiles per wave, resident in registers ----
    h8 bq[QT];
#pragma unroll
    for (int t = 0; t < QT; ++t) {
        const int qi = qblock * QBLK + (wave * QT + t) * 32 + col;
        const float* qp = q + ((size_t)b * NPTS + qi) * 3;
        float x0 = qp[0], x1 = qp[1], x2 = qp[2];
        _Float16 H0, L0, H1, L1, H2, L2, qnh, qnl;
        split16(-2.0f * x0, H0, L0);          // b-side: -2q, split AFTER scaling
        split16(-2.0f * x1, H1, L1);
        split16(-2.0f * x2, H2, L2);
        split16(fmaf(x0, x0, fmaf(x1, x1, x2 * x2)), qnh, qnl);
        h8 b0 = {H0, H1, H2, H0, H1, H2, L0, L1};                           // k0..7
        h8 b1 = {L2, (_Float16)1.0f, (_Float16)1.0f, qnh, qnl,
                 (_Float16)0.0f, (_Float16)0.0f, (_Float16)0.0f};           // k8..15
        bq[t] = hv ? b1 : b0;
    }
    __syncthreads();

    float cm[QT];
#pragma unroll
    for (int t = 0; t < QT; ++t) cm[t] = 3.0e38f;

    // ---- main loop: 1 A-frag read -> 2x (2 MFMAs + 2 trees); d-pair live only ----
    for (int mt = 0; mt < MT; ++mt) {
        const h8 ar = afrag[mt * 64 + lane];   // contiguous 16B/lane, conflict-free
        f16v d0, d1;
        asm("v_mfma_f32_32x32x16_f16 %0, %2, %3, 0\n\t"
            "v_mfma_f32_32x32x16_f16 %1, %2, %4, 0\n\t"
            "s_nop 7\n\t"
            "s_nop 7"
            : "=v"(d0), "=v"(d1)
            : "v"(ar), "v"(bq[0]), "v"(bq[1]));
        cm[0] = fminf(cm[0], tree16(d0));
        cm[1] = fminf(cm[1], tree16(d1));

        f16v d2, d3;
        asm("v_mfma_f32_32x32x16_f16 %0, %2, %3, 0\n\t"
            "v_mfma_f32_32x32x16_f16 %1, %2, %4, 0\n\t"
            "s_nop 7\n\t"
            "s_nop 7"
            : "=v"(d2), "=v"(d3)
            : "v"(ar), "v"(bq[2]), "v"(bq[3]));
        cm[2] = fminf(cm[2], tree16(d2));
        cm[3] = fminf(cm[3], tree16(d3));
    }

    // ---- epilogue: one xor32 per accumulator, coalesced stores ----
    float* pp = partial + ((size_t)(dir * BATCH + b) * SLICES + slice) * NPTS
                        + qblock * QBLK;
#pragma unroll
    for (int t = 0; t < QT; ++t) {
        cm[t] = fminf(cm[t], __shfl_xor(cm[t], 32, 64));   // hv-partner rows
        if (hv == 0)
            pp[(wave * QT + t) * 32 + col] = cm[t];        // 32 lanes, 128B coalesced
    }
}

__global__ __launch_bounds__(TPB) void chamfer_reduce(const float* __restrict__ partial,
                                                      float* __restrict__ out) {
    const int tid = threadIdx.x;
    const int g   = blockIdx.x * TPB + tid;   // [0, 2*BATCH*NPTS)
    const int db  = g >> 13;                  // (dir*BATCH + b)
    const int n   = g & (NPTS - 1);

    const float* p = partial + (size_t)db * SLICES * NPTS + n;
    float v = 3.0e38f;
#pragma unroll
    for (int s = 0; s < SLICES; ++s)
        v = fminf(v, p[(size_t)s * NPTS]);    // coalesced across threads

    float w = v;
#pragma unroll
    for (int off = 32; off > 0; off >>= 1)
        w += __shfl_down(w, off, 64);
    __shared__ float ss[TPB / 64];
    if ((tid & 63) == 0) ss[tid >> 6] = w;
    __syncthreads();
    if (tid == 0)
        atomicAdd(out, (ss[0] + ss[1] + ss[2] + ss[3]) * (1.0f / (float)(BATCH * NPTS)));
}

extern "C" void kernel_launch(void* const* d_in, const int* in_sizes, int n_in,
                              void* d_out, int out_size, void* d_ws, size_t ws_size,
                              hipStream_t stream) {
    const float* x = (const float*)d_in[0];
    const float* y = (const float*)d_in[1];
    float* out = (float*)d_out;
    float* partial = (float*)d_ws;            // 2*4*16*8192*4 = 4 MB

    chamfer_mfma<<<dim3(QBLKS, BATCH * SLICES, 2), TPB, 0, stream>>>(x, y, partial, out);
    chamfer_reduce<<<dim3(2 * BATCH * NPTS / TPB), TPB, 0, stream>>>(partial, out);
}